// Round 1
// baseline (513.889 us; speedup 1.0000x reference)
//
#include <hip/hip_runtime.h>
#include <hip/hip_bf16.h>

#define V_ 32000
#define E_ 512
#define H_ 512
#define B_ 32
#define T_ 48
#define NWG 32   // persistent workgroups in recurrence

typedef __attribute__((ext_vector_type(8))) short bf16x8;
typedef __attribute__((ext_vector_type(4))) float f32x4;

static __device__ __forceinline__ short f2bf(float f) {
  union { __hip_bfloat16 h; short s; } u;
  u.h = __float2bfloat16(f);
  return u.s;
}

// load 8 consecutive f32 (32B aligned) -> bf16x8 fragment
static __device__ __forceinline__ bf16x8 load_cvt8(const float* p) {
  float4 a = *(const float4*)p;
  float4 b = *(const float4*)(p + 4);
  bf16x8 r;
  r[0] = f2bf(a.x); r[1] = f2bf(a.y); r[2] = f2bf(a.z); r[3] = f2bf(a.w);
  r[4] = f2bf(b.x); r[5] = f2bf(b.y); r[6] = f2bf(b.z); r[7] = f2bf(b.w);
  return r;
}

static __device__ __forceinline__ float sigf(float x) {
  return 1.0f / (1.0f + __expf(-x));
}
static __device__ __forceinline__ float tanh_fast(float x) {
  // tanh(x) = 1 - 2/(exp(2x)+1)
  float e = __expf(2.0f * x);
  return (e - 1.0f) / (e + 1.0f);
}

// ---------------------------------------------------------------------------
// Kernel 1: Xg[t][b][j] = x_t[b] @ W_ih^T [j] + b_ih[j] + b_hh[j]
// x_0 = image_features[b], x_t = embedding[token(t,b)]  (t = 1..47)
// grid (48, 8) x 256 threads. MFMA 16x16x32 bf16, fragments direct from global.
// ---------------------------------------------------------------------------
__global__ __launch_bounds__(256) void k_xg(
    const float* __restrict__ img,   // [32][512]
    const int*   __restrict__ gt,    // [32][48]
    const float* __restrict__ emb,   // [32000][512]
    const float* __restrict__ W_ih,  // [2048][512]
    const float* __restrict__ b_ih,
    const float* __restrict__ b_hh,
    float* __restrict__ Xg)          // [48][32][2048]
{
  const int s    = blockIdx.x;
  const int lane = threadIdx.x & 63;
  const int wv   = threadIdx.x >> 6;
  const int nbase = blockIdx.y * 256 + wv * 64;
  const int lr  = lane & 15;
  const int lkb = lane >> 4;

  // A-source row pointers for the two 16-row m-tiles (b = m*16 + lr)
  const float* arow[2];
#pragma unroll
  for (int m = 0; m < 2; ++m) {
    int b = m * 16 + lr;
    const float* src;
    if (s == 0) {
      src = img + b * E_;
    } else {
      int tok = (s == 1) ? 1 : gt[b * T_ + (s - 1)];
      src = emb + (long)tok * E_;
    }
    arow[m] = src;
  }

  f32x4 acc[2][4];
#pragma unroll
  for (int m = 0; m < 2; ++m)
#pragma unroll
    for (int n = 0; n < 4; ++n) acc[m][n] = (f32x4){0.f, 0.f, 0.f, 0.f};

  for (int kt = 0; kt < 16; ++kt) {
    int ko = kt * 32 + lkb * 8;
    bf16x8 a0 = load_cvt8(arow[0] + ko);
    bf16x8 a1 = load_cvt8(arow[1] + ko);
#pragma unroll
    for (int n = 0; n < 4; ++n) {
      const float* wp = W_ih + (long)(nbase + n * 16 + lr) * E_ + ko;
      bf16x8 bw = load_cvt8(wp);
      acc[0][n] = __builtin_amdgcn_mfma_f32_16x16x32_bf16(a0, bw, acc[0][n], 0, 0, 0);
      acc[1][n] = __builtin_amdgcn_mfma_f32_16x16x32_bf16(a1, bw, acc[1][n], 0, 0, 0);
    }
  }

  // D layout: col = lane&15 (= j local), row = (lane>>4)*4 + reg (= b local)
#pragma unroll
  for (int n = 0; n < 4; ++n) {
    int j = nbase + n * 16 + lr;
    float bias = b_ih[j] + b_hh[j];
#pragma unroll
    for (int m = 0; m < 2; ++m) {
#pragma unroll
      for (int r = 0; r < 4; ++r) {
        int b = m * 16 + lkb * 4 + r;
        Xg[((long)(s * B_ + b) * 2048) + j] = acc[m][n][r] + bias;
      }
    }
  }
}

// ---------------------------------------------------------------------------
// Kernel 2: sequential LSTM recurrence. 32 persistent WGs x 128 threads.
// WG w owns hidden dims [16w,16w+16) -> gate rows {g*512+16w+d}, g=0..3.
// W_hh slice = register-resident A-frags. h (bf16) read direct from global
// as B-frags each step. Device-scope counter barrier between steps.
// ---------------------------------------------------------------------------
__global__ __launch_bounds__(128) void k_lstm(
    const float* __restrict__ W_hh,      // [2048][512]
    const float* __restrict__ Xg,        // [48][32][2048]
    unsigned short* __restrict__ hbuf,   // [2][32][512] bf16 (double buffer)
    unsigned short* __restrict__ hs,     // [1504][512] bf16 output states
    unsigned int* __restrict__ cnt)      // barrier counter (zeroed)
{
  __shared__ __align__(16) float gbuf[4 * 32 * 16];  // [gate][b][d] 8KB
  const int wgid = blockIdx.x;   // 0..31
  const int tid  = threadIdx.x;
  const int lane = tid & 63;
  const int wv   = tid >> 6;     // 0..1 ; wave0 -> gates i,f ; wave1 -> g,o
  const int lr   = lane & 15;
  const int lkb  = lane >> 4;

  // A-fragments: W_hh rows for this wave's 2 gates, all 16 k-tiles
  bf16x8 aw[2][16];
#pragma unroll
  for (int gg = 0; gg < 2; ++gg) {
    int grow = (wv * 2 + gg) * 512 + wgid * 16 + lr;
#pragma unroll
    for (int kt = 0; kt < 16; ++kt)
      aw[gg][kt] = load_cvt8(W_hh + (long)grow * E_ + kt * 32 + lkb * 8);
  }

  // persistent cell state: thread owns (b = tid/4, d = (tid%4)*4 .. +3)
  f32x4 cst = (f32x4){0.f, 0.f, 0.f, 0.f};
  const int cb_b  = tid >> 2;
  const int cb_d0 = (tid & 3) * 4;

  for (int t = 0; t < 48; ++t) {
    const unsigned short* hcur = hbuf + (t & 1) * (B_ * H_);

    // B-fragments: h[b][k], col n = b = nt*16+lr, k = kt*32 + lkb*8 + j
    bf16x8 bh[2][16];
#pragma unroll
    for (int nt = 0; nt < 2; ++nt) {
      int b = nt * 16 + lr;
#pragma unroll
      for (int kt = 0; kt < 16; ++kt) {
        int4 v = *(const int4*)(hcur + b * H_ + kt * 32 + lkb * 8);
        bh[nt][kt] = *(bf16x8*)&v;
      }
    }

    // Xg for this lane's outputs (issue early, needed after MFMA)
    float4 xg[2][2];
#pragma unroll
    for (int gg = 0; gg < 2; ++gg) {
      int g = wv * 2 + gg;
#pragma unroll
      for (int nt = 0; nt < 2; ++nt) {
        int b = nt * 16 + lr;
        xg[gg][nt] = *(const float4*)(Xg + (long)(t * B_ + b) * 2048 +
                                      g * 512 + wgid * 16 + lkb * 4);
      }
    }

    f32x4 acc[2][2];
#pragma unroll
    for (int gg = 0; gg < 2; ++gg)
#pragma unroll
      for (int nt = 0; nt < 2; ++nt) acc[gg][nt] = (f32x4){0.f, 0.f, 0.f, 0.f};

#pragma unroll
    for (int kt = 0; kt < 16; ++kt)
#pragma unroll
      for (int gg = 0; gg < 2; ++gg)
#pragma unroll
        for (int nt = 0; nt < 2; ++nt)
          acc[gg][nt] = __builtin_amdgcn_mfma_f32_16x16x32_bf16(
              aw[gg][kt], bh[nt][kt], acc[gg][nt], 0, 0, 0);

    // D: col = b local (lane&15), row = gate-dim d = lkb*4 + reg
#pragma unroll
    for (int gg = 0; gg < 2; ++gg) {
      int g = wv * 2 + gg;
#pragma unroll
      for (int nt = 0; nt < 2; ++nt) {
        int b = nt * 16 + lr;
        f32x4 r = acc[gg][nt];
        r[0] += xg[gg][nt].x; r[1] += xg[gg][nt].y;
        r[2] += xg[gg][nt].z; r[3] += xg[gg][nt].w;
        *(f32x4*)&gbuf[(g * 32 + b) * 16 + lkb * 4] = r;
      }
    }
    __syncthreads();

    // cell update: 4 cells per thread (b = cb_b, d = cb_d0..+3)
    float4 gi = *(const float4*)&gbuf[(0 * 32 + cb_b) * 16 + cb_d0];
    float4 gf = *(const float4*)&gbuf[(1 * 32 + cb_b) * 16 + cb_d0];
    float4 gg_ = *(const float4*)&gbuf[(2 * 32 + cb_b) * 16 + cb_d0];
    float4 go = *(const float4*)&gbuf[(3 * 32 + cb_b) * 16 + cb_d0];
    float iv[4] = {gi.x, gi.y, gi.z, gi.w};
    float fv[4] = {gf.x, gf.y, gf.z, gf.w};
    float gv[4] = {gg_.x, gg_.y, gg_.z, gg_.w};
    float ov[4] = {go.x, go.y, go.z, go.w};
    unsigned short hb[4];
#pragma unroll
    for (int r = 0; r < 4; ++r) {
      float i_ = sigf(iv[r]);
      float f_ = sigf(fv[r]);
      float g_ = tanh_fast(gv[r]);
      float o_ = sigf(ov[r]);
      float c_ = f_ * cst[r] + i_ * g_;
      cst[r] = c_;
      float hv = o_ * tanh_fast(c_);
      hb[r] = (unsigned short)f2bf(hv);
    }
    ushort4 pack = {hb[0], hb[1], hb[2], hb[3]};
    unsigned short* hn = hbuf + ((t + 1) & 1) * (B_ * H_);
    *(ushort4*)(hn + cb_b * H_ + wgid * 16 + cb_d0) = pack;
    if (t >= 1)
      *(ushort4*)(hs + ((long)(t - 1) * B_ + cb_b) * H_ + wgid * 16 + cb_d0) = pack;

    // device-scope barrier
    __syncthreads();
    if (tid == 0) {
      __threadfence();
      __hip_atomic_fetch_add(cnt, 1u, __ATOMIC_RELEASE, __HIP_MEMORY_SCOPE_AGENT);
      unsigned target = (unsigned)NWG * (unsigned)(t + 1);
      while (__hip_atomic_load(cnt, __ATOMIC_ACQUIRE, __HIP_MEMORY_SCOPE_AGENT) < target) {}
    }
    __syncthreads();
  }
}

// ---------------------------------------------------------------------------
// Kernel 3: logits = hs @ W_head^T + b_head -> out[s][b][v], s=1..47
// grid 500 x 256 threads; each wave owns 16 v-rows, W_head frags in registers,
// hs staged per 16-row m-tile in XOR-swizzled LDS.
// ---------------------------------------------------------------------------
__global__ __launch_bounds__(256) void k_head(
    const float* __restrict__ W_head,        // [32000][512]
    const float* __restrict__ b_head,        // [32000]
    const unsigned short* __restrict__ hs,   // [1504][512] bf16
    float* __restrict__ out)                 // [48][32][32000]
{
  __shared__ __align__(16) char alds[16 * 1024];
  const int lane = threadIdx.x & 63;
  const int wv   = threadIdx.x >> 6;
  const int v0   = blockIdx.x * 64 + wv * 16;
  const int lr   = lane & 15;
  const int lkb  = lane >> 4;

  // register-resident B-fragments (W_head rows v0+lr), 16 k-tiles
  bf16x8 bw[16];
#pragma unroll
  for (int kt = 0; kt < 16; ++kt)
    bw[kt] = load_cvt8(W_head + (long)(v0 + lr) * E_ + kt * 32 + lkb * 8);
  float bias = b_head[v0 + lr];

  for (int mt = 0; mt < 94; ++mt) {
    __syncthreads();  // protect previous iteration's LDS reads
    const char* src = (const char*)(hs + (long)mt * 16 * H_);
#pragma unroll
    for (int i = 0; i < 4; ++i) {
      int c = i * 256 + threadIdx.x;   // 1024 x 16B chunks
      int row = c >> 6;
      int cb  = (c & 63) * 16;
      int4 val = *(const int4*)(src + c * 16);
      *(int4*)(alds + row * 1024 + (cb ^ ((row & 7) << 4))) = val;
    }
    __syncthreads();

    f32x4 acc = (f32x4){bias, bias, bias, bias};
#pragma unroll
    for (int kt = 0; kt < 16; ++kt) {
      int cb = kt * 64 + lkb * 16;
      int4 av = *(const int4*)(alds + lr * 1024 + (cb ^ ((lr & 7) << 4)));
      bf16x8 a = *(bf16x8*)&av;
      acc = __builtin_amdgcn_mfma_f32_16x16x32_bf16(a, bw[kt], acc, 0, 0, 0);
    }

    // rows R = mt*16 + lkb*4 + r ; out row = R + 32 (s = R/32 + 1, b = R%32)
#pragma unroll
    for (int r = 0; r < 4; ++r) {
      int R = mt * 16 + lkb * 4 + r;
      out[(long)(R + 32) * V_ + v0 + lr] = acc[r];
    }
  }
}

// ---------------------------------------------------------------------------
extern "C" void kernel_launch(void* const* d_in, const int* in_sizes, int n_in,
                              void* d_out, int out_size, void* d_ws, size_t ws_size,
                              hipStream_t stream) {
  const float* img  = (const float*)d_in[0];
  const int*   gt   = (const int*)d_in[1];
  const float* emb  = (const float*)d_in[2];
  const float* W_ih = (const float*)d_in[3];
  const float* W_hh = (const float*)d_in[4];
  const float* b_ih = (const float*)d_in[5];
  const float* b_hh = (const float*)d_in[6];
  const float* W_hd = (const float*)d_in[7];
  const float* b_hd = (const float*)d_in[8];
  float* out = (float*)d_out;

  char* ws = (char*)d_ws;
  unsigned int*   cnt  = (unsigned int*)(ws);                       // 256 B
  unsigned short* hbuf = (unsigned short*)(ws + 256);               // 65536 B
  unsigned short* hs   = (unsigned short*)(ws + 256 + 65536);       // 1540096 B
  float*          Xg   = (float*)(ws + 256 + 65536 + 1540096);      // 12582912 B

  hipMemsetAsync(cnt, 0, 256, stream);
  hipMemsetAsync(hbuf, 0, B_ * H_ * sizeof(unsigned short), stream);  // h_0 = 0
  hipMemsetAsync(out, 0, (size_t)B_ * V_ * sizeof(float), stream);    // outputs[0] = 0

  dim3 g1(48, 8);
  k_xg<<<g1, 256, 0, stream>>>(img, gt, emb, W_ih, b_ih, b_hh, Xg);
  k_lstm<<<NWG, 128, 0, stream>>>(W_hh, Xg, hbuf, hs, cnt);
  k_head<<<500, 256, 0, stream>>>(W_hd, b_hd, hs, out);
}

// Round 2
// 506.467 us; speedup vs baseline: 1.0147x; 1.0147x over previous
//
#include <hip/hip_runtime.h>
#include <hip/hip_bf16.h>

#define V_ 32000
#define E_ 512
#define H_ 512
#define B_ 32
#define T_ 48
#define NWG 16   // persistent workgroups in recurrence

typedef __attribute__((ext_vector_type(8))) short bf16x8;
typedef __attribute__((ext_vector_type(4))) float f32x4;

static __device__ __forceinline__ short f2bf(float f) {
  union { __hip_bfloat16 h; short s; } u;
  u.h = __float2bfloat16(f);
  return u.s;
}

// load 8 consecutive f32 (32B aligned) -> bf16x8 fragment
static __device__ __forceinline__ bf16x8 load_cvt8(const float* p) {
  float4 a = *(const float4*)p;
  float4 b = *(const float4*)(p + 4);
  bf16x8 r;
  r[0] = f2bf(a.x); r[1] = f2bf(a.y); r[2] = f2bf(a.z); r[3] = f2bf(a.w);
  r[4] = f2bf(b.x); r[5] = f2bf(b.y); r[6] = f2bf(b.z); r[7] = f2bf(b.w);
  return r;
}

static __device__ __forceinline__ float sigf(float x) {
  return 1.0f / (1.0f + __expf(-x));
}
static __device__ __forceinline__ float tanh_fast(float x) {
  float e = __expf(2.0f * x);
  return (e - 1.0f) / (e + 1.0f);
}

// ---------------------------------------------------------------------------
// Kernel 1: Xg[t][b][j] = x_t[b] @ W_ih^T [j] + b_ih[j] + b_hh[j]
// ---------------------------------------------------------------------------
__global__ __launch_bounds__(256) void k_xg(
    const float* __restrict__ img,   // [32][512]
    const int*   __restrict__ gt,    // [32][48]
    const float* __restrict__ emb,   // [32000][512]
    const float* __restrict__ W_ih,  // [2048][512]
    const float* __restrict__ b_ih,
    const float* __restrict__ b_hh,
    float* __restrict__ Xg)          // [48][32][2048]
{
  const int s    = blockIdx.x;
  const int lane = threadIdx.x & 63;
  const int wv   = threadIdx.x >> 6;
  const int nbase = blockIdx.y * 256 + wv * 64;
  const int lr  = lane & 15;
  const int lkb = lane >> 4;

  const float* arow[2];
#pragma unroll
  for (int m = 0; m < 2; ++m) {
    int b = m * 16 + lr;
    const float* src;
    if (s == 0) {
      src = img + b * E_;
    } else {
      int tok = (s == 1) ? 1 : gt[b * T_ + (s - 1)];
      src = emb + (long)tok * E_;
    }
    arow[m] = src;
  }

  f32x4 acc[2][4];
#pragma unroll
  for (int m = 0; m < 2; ++m)
#pragma unroll
    for (int n = 0; n < 4; ++n) acc[m][n] = (f32x4){0.f, 0.f, 0.f, 0.f};

  for (int kt = 0; kt < 16; ++kt) {
    int ko = kt * 32 + lkb * 8;
    bf16x8 a0 = load_cvt8(arow[0] + ko);
    bf16x8 a1 = load_cvt8(arow[1] + ko);
#pragma unroll
    for (int n = 0; n < 4; ++n) {
      const float* wp = W_ih + (long)(nbase + n * 16 + lr) * E_ + ko;
      bf16x8 bw = load_cvt8(wp);
      acc[0][n] = __builtin_amdgcn_mfma_f32_16x16x32_bf16(a0, bw, acc[0][n], 0, 0, 0);
      acc[1][n] = __builtin_amdgcn_mfma_f32_16x16x32_bf16(a1, bw, acc[1][n], 0, 0, 0);
    }
  }

#pragma unroll
  for (int n = 0; n < 4; ++n) {
    int j = nbase + n * 16 + lr;
    float bias = b_ih[j] + b_hh[j];
#pragma unroll
    for (int m = 0; m < 2; ++m) {
#pragma unroll
      for (int r = 0; r < 4; ++r) {
        int b = m * 16 + lkb * 4 + r;
        Xg[((long)(s * B_ + b) * 2048) + j] = acc[m][n][r] + bias;
      }
    }
  }
}

// ---------------------------------------------------------------------------
// Kernel 2: sequential LSTM recurrence. NWG=16 persistent WGs x 256 threads.
// WG w owns hidden dims [32w, 32w+32). Wave wv handles gate wv (2 d-tiles of 16).
// W_hh slice (128 rows x 512, bf16 frags) lives in LDS - immune to L2 inv.
// Relaxed poll + one acquire fence per step.
// ---------------------------------------------------------------------------
__global__ __launch_bounds__(256, 1) void k_lstm(
    const float* __restrict__ W_hh,      // [2048][512]
    const float* __restrict__ Xg,        // [48][32][2048]
    unsigned short* __restrict__ hbuf,   // [2][32][512] bf16 (double buffer)
    unsigned short* __restrict__ hs,     // [1504][512] bf16 output states
    unsigned int* __restrict__ cnt)      // barrier counter (zeroed)
{
  __shared__ __align__(16) char wlds[128 * 1024];   // A-frags for this WG
  __shared__ __align__(16) char gbufc[16 * 1024];   // gate exchange [4][32][32] f32, xor-swizzled
  const int wgid = blockIdx.x;   // 0..15
  const int tid  = threadIdx.x;
  const int lane = tid & 63;
  const int wv   = tid >> 6;     // gate index 0..3 (i,f,g,o)
  const int lr   = lane & 15;
  const int lkb  = lane >> 4;

  // preload W_hh fragments into LDS: gate=wv, d-tiles 0..1, kt 0..15
#pragma unroll
  for (int tile = 0; tile < 2; ++tile) {
    int row = wv * 512 + wgid * 32 + tile * 16 + lr;
#pragma unroll
    for (int kt = 0; kt < 16; ++kt) {
      bf16x8 w = load_cvt8(W_hh + (long)row * E_ + kt * 32 + lkb * 8);
      *(bf16x8*)(wlds + ((((wv * 2 + tile) * 16 + kt) * 64) + lane) * 16) = w;
    }
  }

  // cell-state ownership: thread -> b = tid>>3, d0 = (tid&7)*4
  f32x4 cst = (f32x4){0.f, 0.f, 0.f, 0.f};
  const int cb_b  = tid >> 3;
  const int cb_d0 = (tid & 7) * 4;

  __syncthreads();

  for (int t = 0; t < 48; ++t) {
    const unsigned short* hcur = hbuf + (t & 1) * (B_ * H_);

    // Xg slice for this lane's outputs (independent of h, issue first)
    float4 xg[2][2];
#pragma unroll
    for (int tile = 0; tile < 2; ++tile)
#pragma unroll
      for (int nt = 0; nt < 2; ++nt) {
        int b = nt * 16 + lr;
        xg[tile][nt] = *(const float4*)(Xg + (long)(t * B_ + b) * 2048 +
                                        wv * 512 + wgid * 32 + tile * 16 + lkb * 4);
      }

    // B-fragments: h[b][k]
    bf16x8 bh[2][16];
#pragma unroll
    for (int nt = 0; nt < 2; ++nt) {
      int b = nt * 16 + lr;
#pragma unroll
      for (int kt = 0; kt < 16; ++kt) {
        int4 v = *(const int4*)(hcur + b * H_ + kt * 32 + lkb * 8);
        bh[nt][kt] = *(bf16x8*)&v;
      }
    }

    f32x4 acc[2][2];
#pragma unroll
    for (int tile = 0; tile < 2; ++tile)
#pragma unroll
      for (int nt = 0; nt < 2; ++nt) acc[tile][nt] = (f32x4){0.f, 0.f, 0.f, 0.f};

#pragma unroll
    for (int kt = 0; kt < 16; ++kt) {
      bf16x8 a0 = *(const bf16x8*)(wlds + ((((wv * 2 + 0) * 16 + kt) * 64) + lane) * 16);
      bf16x8 a1 = *(const bf16x8*)(wlds + ((((wv * 2 + 1) * 16 + kt) * 64) + lane) * 16);
      acc[0][0] = __builtin_amdgcn_mfma_f32_16x16x32_bf16(a0, bh[0][kt], acc[0][0], 0, 0, 0);
      acc[0][1] = __builtin_amdgcn_mfma_f32_16x16x32_bf16(a0, bh[1][kt], acc[0][1], 0, 0, 0);
      acc[1][0] = __builtin_amdgcn_mfma_f32_16x16x32_bf16(a1, bh[0][kt], acc[1][0], 0, 0, 0);
      acc[1][1] = __builtin_amdgcn_mfma_f32_16x16x32_bf16(a1, bh[1][kt], acc[1][1], 0, 0, 0);
    }

    // D: col = b (lane&15), row = d local = lkb*4 + reg.  gbuf xor-swizzled:
    // byte = (gate*32 + b)*128 + ((d*4) ^ ((b&7)<<4))
#pragma unroll
    for (int tile = 0; tile < 2; ++tile)
#pragma unroll
      for (int nt = 0; nt < 2; ++nt) {
        int b = nt * 16 + lr;
        f32x4 r = acc[tile][nt];
        r[0] += xg[tile][nt].x; r[1] += xg[tile][nt].y;
        r[2] += xg[tile][nt].z; r[3] += xg[tile][nt].w;
        int byte = (wv * 32 + b) * 128 + (((tile * 16 + lkb * 4) * 4) ^ ((b & 7) << 4));
        *(f32x4*)(gbufc + byte) = r;
      }
    __syncthreads();

    // cell update: 4 cells per thread (b = cb_b, d = cb_d0..+3)
    int rb = ((cb_d0 * 4) ^ ((cb_b & 7) << 4));
    float4 gi = *(const float4*)(gbufc + (0 * 32 + cb_b) * 128 + rb);
    float4 gf = *(const float4*)(gbufc + (1 * 32 + cb_b) * 128 + rb);
    float4 gg_ = *(const float4*)(gbufc + (2 * 32 + cb_b) * 128 + rb);
    float4 go = *(const float4*)(gbufc + (3 * 32 + cb_b) * 128 + rb);
    float iv[4] = {gi.x, gi.y, gi.z, gi.w};
    float fv[4] = {gf.x, gf.y, gf.z, gf.w};
    float gv[4] = {gg_.x, gg_.y, gg_.z, gg_.w};
    float ov[4] = {go.x, go.y, go.z, go.w};
    unsigned short hb[4];
#pragma unroll
    for (int r = 0; r < 4; ++r) {
      float i_ = sigf(iv[r]);
      float f_ = sigf(fv[r]);
      float g_ = tanh_fast(gv[r]);
      float o_ = sigf(ov[r]);
      float c_ = f_ * cst[r] + i_ * g_;
      cst[r] = c_;
      float hv = o_ * tanh_fast(c_);
      hb[r] = (unsigned short)f2bf(hv);
    }
    ushort4 pack = {hb[0], hb[1], hb[2], hb[3]};

    if (t < 47) {
      unsigned short* hn = hbuf + ((t + 1) & 1) * (B_ * H_);
      *(ushort4*)(hn + cb_b * H_ + wgid * 32 + cb_d0) = pack;

      __syncthreads();  // all h stores issued before release
      if (tid == 0) {
        __hip_atomic_fetch_add(cnt, 1u, __ATOMIC_RELEASE, __HIP_MEMORY_SCOPE_AGENT);
        unsigned target = (unsigned)NWG * (unsigned)(t + 1);
        while (__hip_atomic_load(cnt, __ATOMIC_RELAXED, __HIP_MEMORY_SCOPE_AGENT) < target)
          __builtin_amdgcn_s_sleep(1);
      }
      __syncthreads();
      __builtin_amdgcn_fence(__ATOMIC_ACQUIRE, "agent");
    }

    // hs store off the critical path (consumed only after kernel end)
    if (t >= 1)
      *(ushort4*)(hs + ((long)(t - 1) * B_ + cb_b) * H_ + wgid * 32 + cb_d0) = pack;
  }
}

// ---------------------------------------------------------------------------
// Kernel 3: logits = hs @ W_head^T + b_head -> out[s][b][v], s=1..47
// ---------------------------------------------------------------------------
__global__ __launch_bounds__(256) void k_head(
    const float* __restrict__ W_head,        // [32000][512]
    const float* __restrict__ b_head,        // [32000]
    const unsigned short* __restrict__ hs,   // [1504][512] bf16
    float* __restrict__ out)                 // [48][32][32000]
{
  __shared__ __align__(16) char alds[16 * 1024];
  const int lane = threadIdx.x & 63;
  const int wv   = threadIdx.x >> 6;
  const int v0   = blockIdx.x * 64 + wv * 16;
  const int lr   = lane & 15;
  const int lkb  = lane >> 4;

  bf16x8 bw[16];
#pragma unroll
  for (int kt = 0; kt < 16; ++kt)
    bw[kt] = load_cvt8(W_head + (long)(v0 + lr) * E_ + kt * 32 + lkb * 8);
  float bias = b_head[v0 + lr];

  for (int mt = 0; mt < 94; ++mt) {
    __syncthreads();
    const char* src = (const char*)(hs + (long)mt * 16 * H_);
#pragma unroll
    for (int i = 0; i < 4; ++i) {
      int c = i * 256 + threadIdx.x;   // 1024 x 16B chunks
      int row = c >> 6;
      int cb  = (c & 63) * 16;
      int4 val = *(const int4*)(src + c * 16);
      *(int4*)(alds + row * 1024 + (cb ^ ((row & 7) << 4))) = val;
    }
    __syncthreads();

    f32x4 acc = (f32x4){bias, bias, bias, bias};
#pragma unroll
    for (int kt = 0; kt < 16; ++kt) {
      int cb = kt * 64 + lkb * 16;
      int4 av = *(const int4*)(alds + lr * 1024 + (cb ^ ((lr & 7) << 4)));
      bf16x8 a = *(bf16x8*)&av;
      acc = __builtin_amdgcn_mfma_f32_16x16x32_bf16(a, bw[kt], acc, 0, 0, 0);
    }

#pragma unroll
    for (int r = 0; r < 4; ++r) {
      int R = mt * 16 + lkb * 4 + r;
      out[(long)(R + 32) * V_ + v0 + lr] = acc[r];
    }
  }
}

// ---------------------------------------------------------------------------
extern "C" void kernel_launch(void* const* d_in, const int* in_sizes, int n_in,
                              void* d_out, int out_size, void* d_ws, size_t ws_size,
                              hipStream_t stream) {
  const float* img  = (const float*)d_in[0];
  const int*   gt   = (const int*)d_in[1];
  const float* emb  = (const float*)d_in[2];
  const float* W_ih = (const float*)d_in[3];
  const float* W_hh = (const float*)d_in[4];
  const float* b_ih = (const float*)d_in[5];
  const float* b_hh = (const float*)d_in[6];
  const float* W_hd = (const float*)d_in[7];
  const float* b_hd = (const float*)d_in[8];
  float* out = (float*)d_out;

  char* ws = (char*)d_ws;
  unsigned int*   cnt  = (unsigned int*)(ws);                       // 256 B
  unsigned short* hbuf = (unsigned short*)(ws + 256);               // 65536 B
  unsigned short* hs   = (unsigned short*)(ws + 256 + 65536);       // 1540096 B
  float*          Xg   = (float*)(ws + 256 + 65536 + 1540096);      // 12582912 B

  hipMemsetAsync(cnt, 0, 256, stream);
  hipMemsetAsync(hbuf, 0, B_ * H_ * sizeof(unsigned short), stream);  // h_0 = 0
  hipMemsetAsync(out, 0, (size_t)B_ * V_ * sizeof(float), stream);    // outputs[0] = 0

  dim3 g1(48, 8);
  k_xg<<<g1, 256, 0, stream>>>(img, gt, emb, W_ih, b_ih, b_hh, Xg);
  k_lstm<<<NWG, 256, 0, stream>>>(W_hh, Xg, hbuf, hs, cnt);
  k_head<<<500, 256, 0, stream>>>(W_hd, b_hd, hs, out);
}